// Round 7
// baseline (411.979 us; speedup 1.0000x reference)
//
#include <hip/hip_runtime.h>
#include <math.h>

#define D     1024
#define H     256
#define BLOW  2048
#define BTOT  4096
#define NCHUNK 64   // 4096 / 64 col chunks (per-wave) in the NT-LSE GEMM

using bf16x8 = __attribute__((ext_vector_type(8))) __bf16;
using f32x4  = __attribute__((ext_vector_type(4))) float;

// ---------------- workspace layout ----------------
// fp32 region (float units)
static const size_t OFF_ZALL = 0;                 // 4096*1024
static const size_t OFF_C    = 4194304;           // C fp32
static const size_t OFF_D2   = 8388608;           // D2 = z_tumor @ W0 (fp32)
static const size_t T0       = 12582912;
static const size_t OFF_SALL = T0;                // 4096  (s_norm follows contiguously)
static const size_t OFF_SNORM= T0 + 4096;         // 4096
static const size_t OFF_EGRP = T0 + 8192;         // 4096
static const size_t OFF_ENORM= T0 + 16384;        // 4096
static const size_t OFF_PLOW = T0 + 20480;        // 1024 x4 contiguous
static const size_t OFF_PHIGH= T0 + 21504;
static const size_t OFF_PNORM= T0 + 22528;
static const size_t OFF_PALL = T0 + 23552;
static const size_t OFF_ZNV  = T0 + 24576;        // 1024
static const size_t OFF_WNORM= T0 + 25600;        // 1024
static const size_t OFF_BIASC= T0 + 26624;        // 1024
static const size_t OFF_STATS= T0 + 27648;        // 16
static const size_t OFF_ACC  = T0 + 27664;        // 16
static const size_t OFF_NZ   = T0 + 27680;        // 4096
static const size_t OFF_DT   = T0 + 31776;        // 4096
static const size_t OFF_G    = T0 + 35872;        // 4096
static const size_t OFF_DIAG = T0 + 39968;        // 4096
static const size_t OFF_PART = T0 + 44064;        // float2[64][4096] = 524288 floats
static const size_t BF_BASE_F = 13160448;         // bf16 region starts here (float units)
// bf16 offsets (ushort units)
static const size_t BF_ZALLN= 0;                  // [z_all(4096) ; z_normal(4096)] x 1024
static const size_t BF_ZHAT = 8388608;
static const size_t BF_ZTUM = 12582912;
static const size_t BF_ZBAR = 16777216;
static const size_t BF_C    = 20971520;
static const size_t BF_W0T  = 25165824;           // 1024x1024
static const size_t BF_W1T  = 26214400;
static const size_t BF_WA1T = 27262976;           // 256x1024

// ---------------- helpers ----------------
__device__ inline unsigned short f2bf(float f){
  unsigned u = __float_as_uint(f);
  u += 0x7fffu + ((u >> 16) & 1u);
  return (unsigned short)(u >> 16);
}
__device__ inline float wave_sum(float v){
#pragma unroll
  for (int o = 32; o > 0; o >>= 1) v += __shfl_xor(v, o);
  return v;
}
__device__ inline float wave_maxf(float v){
#pragma unroll
  for (int o = 32; o > 0; o >>= 1) v = fmaxf(v, __shfl_xor(v, o));
  return v;
}
__device__ inline float block_sum(float v, float* sb){
  v = wave_sum(v);
  __syncthreads();
  if ((threadIdx.x & 63) == 0) sb[threadIdx.x >> 6] = v;
  __syncthreads();
  return sb[0] + sb[1] + sb[2] + sb[3];
}
__device__ inline float block_maxf(float v, float* sb){
  v = wave_maxf(v);
  __syncthreads();
  if ((threadIdx.x & 63) == 0) sb[threadIdx.x >> 6] = v;
  __syncthreads();
  return fmaxf(fmaxf(sb[0], sb[1]), fmaxf(sb[2], sb[3]));
}

// async global->LDS, 16 B per lane (dest = wave-uniform base + lane*16)
__device__ inline void gload16(const unsigned short* g, unsigned short* l){
  __builtin_amdgcn_global_load_lds(
      (const __attribute__((address_space(1))) unsigned int*)g,
      (__attribute__((address_space(3))) unsigned int*)l, 16, 0, 0);
}

// ---------------- fused prep: concat+conv / conv z_normal / conv z_bar ----------------
__global__ __launch_bounds__(256) void k_prep(const float* __restrict__ zl,
        const float* __restrict__ zh, const float* __restrict__ znorm,
        const float* __restrict__ zbar, float* __restrict__ za,
        unsigned short* __restrict__ zalln_bf, unsigned short* __restrict__ zbar_bf){
  int row = blockIdx.x, t = threadIdx.x, job = blockIdx.z;
  if (job == 0){
    const float4* src = (const float4*)((row < BLOW) ? (zl + (size_t)row * D)
                                                     : (zh + (size_t)(row - BLOW) * D));
    float4 v = src[t];
    ((float4*)(za + (size_t)row * D))[t] = v;
    *(ushort4*)(zalln_bf + (size_t)row * D + t * 4) =
        make_ushort4(f2bf(v.x), f2bf(v.y), f2bf(v.z), f2bf(v.w));
  } else if (job == 1){
    float4 v = ((const float4*)(znorm + (size_t)row * D))[t];
    *(ushort4*)(zalln_bf + (size_t)(BTOT + row) * D + t * 4) =
        make_ushort4(f2bf(v.x), f2bf(v.y), f2bf(v.z), f2bf(v.w));
  } else {
    float4 v = ((const float4*)(zbar + (size_t)row * D))[t];
    *(ushort4*)(zbar_bf + (size_t)row * D + t * 4) =
        make_ushort4(f2bf(v.x), f2bf(v.y), f2bf(v.z), f2bf(v.w));
  }
}

// transpose+convert all three weights in one launch
__global__ __launch_bounds__(256) void k_tconv3(const float* __restrict__ W0,
        const float* __restrict__ W1, const float* __restrict__ Wa1,
        unsigned short* __restrict__ W0T, unsigned short* __restrict__ W1T,
        unsigned short* __restrict__ Wa1T){
  __shared__ float tile[32][33];
  int z = blockIdx.z;
  const float* in; unsigned short* out; int R, C;
  if (z == 0){ in = W0; out = W0T; R = D; C = D; }
  else if (z == 1){ in = W1; out = W1T; R = D; C = D; }
  else { if (blockIdx.x >= 8) return; in = Wa1; out = Wa1T; R = D; C = H; }
  int t = threadIdx.x;
  int lr = t >> 3;
  int lc = (t & 7) << 2;
  int gr = blockIdx.y * 32, gc = blockIdx.x * 32;
  float4 v = *(const float4*)(in + (size_t)(gr + lr) * C + gc + lc);
  tile[lr][lc + 0] = v.x; tile[lr][lc + 1] = v.y; tile[lr][lc + 2] = v.z; tile[lr][lc + 3] = v.w;
  __syncthreads();
  ushort4 o = make_ushort4(f2bf(tile[lc + 0][lr]), f2bf(tile[lc + 1][lr]),
                           f2bf(tile[lc + 2][lr]), f2bf(tile[lc + 3][lr]));
  *(ushort4*)(out + (size_t)(gc + lr) * R + gr + lc) = o;
}

// zero the scattered accumulator ranges in one launch
__global__ __launch_bounds__(256) void k_zero13(float* __restrict__ ws){
  int i = blockIdx.x * 256 + threadIdx.x;
  if (i < 8192) ws[OFF_SALL + i] = 0.f;                   // s_all + s_norm
  else if (i < 12288) ws[OFF_PLOW + i - 8192] = 0.f;      // P_low..P_all
  else if (i < 13312) ws[OFF_WNORM + i - 12288] = 0.f;
  else if (i < 13328) ws[OFF_ACC + i - 13312] = 0.f;
}

// ---------------- 128x128 double-buffered core (4 waves, 64x64 each) ----------------
__device__ inline void mfma_core_db(const unsigned short* __restrict__ A,
                                    const unsigned short* __restrict__ B,
                                    int row0, int col0,
                                    unsigned short* lds,
                                    f32x4 acc[4][4]){
  int t = threadIdx.x;
  int l = t & 63, w = t >> 6;
  int wrow = w >> 1, wcol = w & 1;
  int g = l >> 4, c15 = l & 15;
  const unsigned short* a0 = A + (size_t)(row0 + (t >> 2)) * 1024 + ((t & 3) << 3);
  const unsigned short* a1 = a0 + (size_t)64 * 1024;
  const unsigned short* b0 = B + (size_t)(col0 + (t >> 2)) * 1024 + ((t & 3) << 3);
  const unsigned short* b1 = b0 + (size_t)64 * 1024;
  int sd = w * 512;
  int abase = (wrow * 64 + c15) * 32 + g * 8;
  int bbase = 4096 + (wcol * 64 + c15) * 32 + g * 8;
  unsigned short* buf = lds;
  unsigned short* nxt = lds + 8192;
  gload16(a0, buf + sd);
  gload16(a1, buf + 2048 + sd);
  gload16(b0, buf + 4096 + sd);
  gload16(b1, buf + 6144 + sd);
  __syncthreads();
  for (int kb = 0; kb < 1024; kb += 32){
    if (kb + 32 < 1024){
      gload16(a0 + kb + 32, nxt + sd);
      gload16(a1 + kb + 32, nxt + 2048 + sd);
      gload16(b0 + kb + 32, nxt + 4096 + sd);
      gload16(b1 + kb + 32, nxt + 6144 + sd);
    }
    bf16x8 af[4], bfr[4];
#pragma unroll
    for (int m = 0; m < 4; ++m) af[m]  = *(const bf16x8*)&buf[abase + m * 512];
#pragma unroll
    for (int n = 0; n < 4; ++n) bfr[n] = *(const bf16x8*)&buf[bbase + n * 512];
#pragma unroll
    for (int m = 0; m < 4; ++m)
#pragma unroll
      for (int n = 0; n < 4; ++n)
        acc[m][n] = __builtin_amdgcn_mfma_f32_16x16x32_bf16(af[m], bfr[n], acc[m][n], 0, 0, 0);
    __syncthreads();
    unsigned short* tmp = buf; buf = nxt; nxt = tmp;
  }
}

// ---------------- 256x128 core: 4 waves, each owns 128x64 (8x4 frags) ----------------
// MFMA-bound geometry: per wave-K-step 32 MFMA (~154cy) vs 12 ds_read_b128 (~144cy).
// LDS per buffer: A 256x32 (8192 us) + B 128x32 (4096 us) = 12288 us; x2 dbuf = 48KB.
__device__ inline void mfma_core256(const unsigned short* __restrict__ A,
                                    const unsigned short* __restrict__ B,
                                    int row0, int col0,
                                    unsigned short* lds,
                                    f32x4 acc[8][4]){
  int t = threadIdx.x;
  int l = t & 63, w = t >> 6;
  int wr = w >> 1, wc = w & 1;
  int g = l >> 4, c15 = l & 15;
  // A: 1024 chunks of 16B, thread t covers c = t + 256j (j=0..3); row=c>>2, koff=(c&3)*8
  const unsigned short* aP[4];
  const unsigned short* bP[2];
#pragma unroll
  for (int j = 0; j < 4; ++j){
    int c = t + 256 * j;
    aP[j] = A + (size_t)(row0 + (c >> 2)) * 1024 + ((c & 3) << 3);
  }
#pragma unroll
  for (int j = 0; j < 2; ++j){
    int c = t + 256 * j;
    bP[j] = B + (size_t)(col0 + (c >> 2)) * 1024 + ((c & 3) << 3);
  }
  int sd = w * 512;                 // wave-uniform lane0 chunk base (ushorts)
  int abase = (wr * 128 + c15) * 32 + g * 8;
  int bbase = 8192 + (wc * 64 + c15) * 32 + g * 8;
  unsigned short* buf = lds;
  unsigned short* nxt = lds + 12288;
#pragma unroll
  for (int j = 0; j < 4; ++j) gload16(aP[j], buf + sd + j * 2048);
#pragma unroll
  for (int j = 0; j < 2; ++j) gload16(bP[j], buf + 8192 + sd + j * 2048);
  __syncthreads();
  for (int kb = 0; kb < 1024; kb += 32){
    if (kb + 32 < 1024){
#pragma unroll
      for (int j = 0; j < 4; ++j) gload16(aP[j] + kb + 32, nxt + sd + j * 2048);
#pragma unroll
      for (int j = 0; j < 2; ++j) gload16(bP[j] + kb + 32, nxt + 8192 + sd + j * 2048);
    }
    bf16x8 bfr[4];
#pragma unroll
    for (int n = 0; n < 4; ++n) bfr[n] = *(const bf16x8*)&buf[bbase + n * 512];
#pragma unroll
    for (int m = 0; m < 8; ++m){
      bf16x8 af = *(const bf16x8*)&buf[abase + m * 512];
#pragma unroll
      for (int n = 0; n < 4; ++n)
        acc[m][n] = __builtin_amdgcn_mfma_f32_16x16x32_bf16(af, bfr[n], acc[m][n], 0, 0, 0);
    }
    __syncthreads();
    unsigned short* tmp = buf; buf = nxt; nxt = tmp;
  }
}

// scores: S[row] += sum_col tanh(z@Wa1 + ba1)[col] * Wa2[col]  (ba2 dropped: softmax-invariant)
__global__ __launch_bounds__(256) void k_scores_bf(const unsigned short* __restrict__ Zbf,
        const unsigned short* __restrict__ Wa1T, const float* __restrict__ ba1,
        const float* __restrict__ Wa2, float* __restrict__ S){
  __shared__ __align__(16) unsigned short smem[16384];
  f32x4 acc[4][4];
  f32x4 zz = {0.f, 0.f, 0.f, 0.f};
#pragma unroll
  for (int m = 0; m < 4; ++m)
#pragma unroll
    for (int n = 0; n < 4; ++n) acc[m][n] = zz;
  int row0 = blockIdx.y * 128, col0 = blockIdx.x * 128;
  mfma_core_db(Zbf, Wa1T, row0, col0, smem, acc);
  int t = threadIdx.x, l = t & 63, w = t >> 6, wrow = w >> 1, wcol = w & 1;
  int g = l >> 4, c15 = l & 15;
#pragma unroll
  for (int m = 0; m < 4; ++m){
#pragma unroll
    for (int r = 0; r < 4; ++r){
      float v = 0.f;
#pragma unroll
      for (int n = 0; n < 4; ++n){
        int col = col0 + wcol * 64 + n * 16 + c15;
        float x = acc[m][n][r] + ba1[col];
        float e = __expf(2.f * x);
        v += (1.f - 2.f / (e + 1.f)) * Wa2[col];
      }
      v += __shfl_xor(v, 1); v += __shfl_xor(v, 2); v += __shfl_xor(v, 4); v += __shfl_xor(v, 8);
      if (c15 == 0) atomicAdd(&S[row0 + wrow * 64 + m * 16 + 4 * g + r], v);
    }
  }
}

// C / D2 kernel, grid (8, 32, 2):
// z=0: C = zhat@W0 + zbar@W1 + biasC (fp32 + bf16 mirror)
// z=1: D2 = ztum@W0 (fp32, no bias) — PT = C + D2 is formed on the fly downstream
__global__ __launch_bounds__(256) void k_gemm_cpt(const unsigned short* __restrict__ Zhat,
        const unsigned short* __restrict__ Zbar, const unsigned short* __restrict__ Ztum,
        const unsigned short* __restrict__ W0T, const unsigned short* __restrict__ W1T,
        const float* __restrict__ biasC, float* __restrict__ C,
        unsigned short* __restrict__ Cbf, float* __restrict__ D2){
  __shared__ __align__(16) unsigned short smem[16384];
  f32x4 acc[4][4];
  f32x4 zz = {0.f, 0.f, 0.f, 0.f};
#pragma unroll
  for (int m = 0; m < 4; ++m)
#pragma unroll
    for (int n = 0; n < 4; ++n) acc[m][n] = zz;
  int row0 = blockIdx.y * 128, col0 = blockIdx.x * 128;
  int t = threadIdx.x, l = t & 63, w = t >> 6, wrow = w >> 1, wcol = w & 1;
  int g = l >> 4, c15 = l & 15;
  if (blockIdx.z == 0){
    mfma_core_db(Zhat, W0T, row0, col0, smem, acc);
    mfma_core_db(Zbar, W1T, row0, col0, smem, acc);
#pragma unroll
    for (int m = 0; m < 4; ++m){
      int row = row0 + wrow * 64 + m * 16 + 4 * g;
#pragma unroll
      for (int n = 0; n < 4; ++n){
        int col = col0 + wcol * 64 + n * 16 + c15;
        float bv = biasC[col];
#pragma unroll
        for (int r = 0; r < 4; ++r){
          float v = acc[m][n][r] + bv;
          size_t idx = (size_t)(row + r) * 1024 + col;
          C[idx] = v;
          Cbf[idx] = f2bf(v);
        }
      }
    }
  } else {
    mfma_core_db(Ztum, W0T, row0, col0, smem, acc);
#pragma unroll
    for (int m = 0; m < 4; ++m){
      int row = row0 + wrow * 64 + m * 16 + 4 * g;
#pragma unroll
      for (int n = 0; n < 4; ++n){
        int col = col0 + wcol * 64 + n * 16 + c15;
#pragma unroll
        for (int r = 0; r < 4; ++r)
          D2[(size_t)(row + r) * 1024 + col] = acc[m][n][r];
      }
    }
  }
}

// NT GEMM M = z_all . C^T with fused per-64col-chunk row (max,sumexp) partials + diag.
// 256x128 tile core; grid (32, 16).
__global__ __launch_bounds__(256) void k_gemm_lse(const unsigned short* __restrict__ A,
        const unsigned short* __restrict__ B, float2* __restrict__ partials,
        float* __restrict__ diagM){
  __shared__ __align__(16) unsigned short smem[24576];
  f32x4 acc[8][4];
  f32x4 zz = {0.f, 0.f, 0.f, 0.f};
#pragma unroll
  for (int m = 0; m < 8; ++m)
#pragma unroll
    for (int n = 0; n < 4; ++n) acc[m][n] = zz;
  int row0 = blockIdx.y * 256, col0 = blockIdx.x * 128;
  mfma_core256(A, B, row0, col0, smem, acc);
  int t = threadIdx.x, l = t & 63, w = t >> 6, wr = w >> 1, wc = w & 1;
  int g = l >> 4, c15 = l & 15;
  int chunk = blockIdx.x * 2 + wc;
#pragma unroll
  for (int m = 0; m < 8; ++m){
#pragma unroll
    for (int r = 0; r < 4; ++r){
      float lm = acc[m][0][r];
#pragma unroll
      for (int n = 1; n < 4; ++n) lm = fmaxf(lm, acc[m][n][r]);
      lm = fmaxf(lm, __shfl_xor(lm, 1));
      lm = fmaxf(lm, __shfl_xor(lm, 2));
      lm = fmaxf(lm, __shfl_xor(lm, 4));
      lm = fmaxf(lm, __shfl_xor(lm, 8));
      float ls = 0.f;
#pragma unroll
      for (int n = 0; n < 4; ++n) ls += __expf(acc[m][n][r] - lm);
      ls += __shfl_xor(ls, 1); ls += __shfl_xor(ls, 2); ls += __shfl_xor(ls, 4); ls += __shfl_xor(ls, 8);
      if (c15 == 0)
        partials[(size_t)chunk * BTOT + (row0 + wr * 128 + m * 16 + 4 * g + r)] = make_float2(lm, ls);
    }
  }
  // diagonal: rows [row0,row0+256) x cols [col0,col0+128) touch the diagonal?
  if (col0 >= row0 && col0 < row0 + 256){
#pragma unroll
    for (int m = 0; m < 8; ++m){
#pragma unroll
      for (int n = 0; n < 4; ++n){
        int col = col0 + wc * 64 + n * 16 + c15;
#pragma unroll
        for (int r = 0; r < 4; ++r){
          int row = row0 + wr * 128 + m * 16 + 4 * g + r;
          if (row == col) diagM[row] = acc[m][n][r];
        }
      }
    }
  }
}

// ---------------- softmax stats (register-resident, one global pass) ----------------
// stats: 0 ml, 1 tl, 2 mh, 3 th, 4 ma, 5 ta, 6 mn, 7 tn, 8 sl=exp(ml-ma), 9 sh=exp(mh-ma)
__global__ __launch_bounds__(256) void k_stats(const float* __restrict__ s_all,
        const float* __restrict__ s_norm, float* __restrict__ e_grp,
        float* __restrict__ e_norm, float* __restrict__ stats){
  __shared__ float sb[4];
  int t = threadIdx.x;
  float va[16], vn[16];
#pragma unroll
  for (int j = 0; j < 16; ++j) va[j] = s_all[t + 256 * j];
#pragma unroll
  for (int j = 0; j < 16; ++j) vn[j] = s_norm[t + 256 * j];
  float m = -1e30f;
#pragma unroll
  for (int j = 0; j < 8; ++j) m = fmaxf(m, va[j]);
  float ml = block_maxf(m, sb);
  m = -1e30f;
#pragma unroll
  for (int j = 8; j < 16; ++j) m = fmaxf(m, va[j]);
  float mh = block_maxf(m, sb);
  m = -1e30f;
#pragma unroll
  for (int j = 0; j < 16; ++j) m = fmaxf(m, vn[j]);
  float mn = block_maxf(m, sb);
  float ma = fmaxf(ml, mh);
  float a = 0.f;
#pragma unroll
  for (int j = 0; j < 8; ++j){ float e = __expf(va[j] - ml); e_grp[t + 256 * j] = e; a += e; }
  float tl = block_sum(a, sb);
  a = 0.f;
#pragma unroll
  for (int j = 8; j < 16; ++j){ float e = __expf(va[j] - mh); e_grp[t + 256 * j] = e; a += e; }
  float th = block_sum(a, sb);
  a = 0.f;
#pragma unroll
  for (int j = 0; j < 16; ++j){ float e = __expf(vn[j] - mn); e_norm[t + 256 * j] = e; a += e; }
  float tn = block_sum(a, sb);
  if (t == 0){
    float sl = __expf(ml - ma), sh = __expf(mh - ma);
    stats[0] = ml; stats[1] = tl; stats[2] = mh; stats[3] = th;
    stats[4] = ma; stats[5] = tl * sl + th * sh; stats[6] = mn; stats[7] = tn;
    stats[8] = sl; stats[9] = sh;
  }
}

// P_g[col] = sum_rows e_row * x[row][col]; groups: 0 low, 1 high, 2 norm.
__global__ __launch_bounds__(256) void k_pvec(const float* __restrict__ z_all,
        const float* __restrict__ z_normal, const float* __restrict__ e_grp,
        const float* __restrict__ e_norm, float* __restrict__ P){
  int gz = blockIdx.z;
  const float* X; const float* E; float* Pg; int nr;
  if (gz == 0){ X = z_all;                         E = e_grp;        Pg = P;        nr = BLOW; }
  else if (gz == 1){ X = z_all + (size_t)BLOW * D; E = e_grp + BLOW; Pg = P + 1024; nr = BLOW; }
  else { X = z_normal;                             E = e_norm;       Pg = P + 2048; nr = BTOT; }
  int r0 = blockIdx.y * 16;
  if (r0 >= nr) return;
  int c4 = threadIdx.x * 4;
  float4 a = make_float4(0.f, 0.f, 0.f, 0.f);
#pragma unroll 4
  for (int r = r0; r < r0 + 16; ++r){
    float e = E[r];
    float4 x = *(const float4*)(X + (size_t)r * D + c4);
    a.x = fmaf(e, x.x, a.x); a.y = fmaf(e, x.y, a.y);
    a.z = fmaf(e, x.z, a.z); a.w = fmaf(e, x.w, a.w);
  }
  atomicAdd(&Pg[c4 + 0], a.x);
  atomicAdd(&Pg[c4 + 1], a.y);
  atomicAdd(&Pg[c4 + 2], a.z);
  atomicAdd(&Pg[c4 + 3], a.w);
}

// P_all = sl*P_low + sh*P_high; znv = P_norm / tn; biasC = 2 b0 + b1
__global__ __launch_bounds__(256) void k_smallvec(const float* __restrict__ P,
        const float* __restrict__ stats, const float* __restrict__ b0,
        const float* __restrict__ b1, float* __restrict__ P_all,
        float* __restrict__ znv, float* __restrict__ biasC){
  int c = blockIdx.x * 256 + threadIdx.x;
  znv[c] = P[2048 + c] / stats[7];
  biasC[c] = 2.f * b0[c] + b1[c];
  P_all[c] = stats[8] * P[c] + stats[9] * P[1024 + c];
}

__global__ __launch_bounds__(256) void k_wnorm(const float* __restrict__ znv,
        const float* __restrict__ W0, float* __restrict__ w_norm){
  int col = blockIdx.x * 256 + threadIdx.x;
  int kc = blockIdx.y;
  float a = 0.f;
  for (int k = kc * 128; k < kc * 128 + 128; ++k)
    a = fmaf(znv[k], W0[(size_t)k * D + col], a);
  atomicAdd(&w_norm[col], a);
}

// z_hat / z_tumor rows (bf16 out) + cos(z,z_hat), cos(z,z_bar) reductions
__global__ __launch_bounds__(256) void k_zhat(const float* __restrict__ z_all,
        const float* __restrict__ z_bar, const float* __restrict__ e_grp,
        const float* __restrict__ stats,
        const float* __restrict__ P_low, const float* __restrict__ P_high,
        const float* __restrict__ P_all, unsigned short* __restrict__ zhat_bf,
        unsigned short* __restrict__ ztum_bf, float* __restrict__ nz_arr,
        float* __restrict__ accum){
  __shared__ float sb[4];
  int i = blockIdx.x, t = threadIdx.x;
  const float* Pg = (i < BLOW) ? P_low : P_high;
  float Tg = (i < BLOW) ? stats[1] : stats[3];
  float Ta = stats[5];
  float eg = e_grp[i];
  float ea = eg * ((i < BLOW) ? stats[8] : stats[9]);
  float ig = 1.f / (Tg - eg), ia = 1.f / (Ta - ea);
  size_t base = (size_t)i * D;
  float4 x  = ((const float4*)(z_all + base))[t];
  float4 pg = ((const float4*)Pg)[t];
  float4 pa = ((const float4*)P_all)[t];
  float4 zb = ((const float4*)(z_bar + base))[t];
  float4 zh, zt;
  zh.x = (pg.x - eg * x.x) * ig; zh.y = (pg.y - eg * x.y) * ig;
  zh.z = (pg.z - eg * x.z) * ig; zh.w = (pg.w - eg * x.w) * ig;
  zt.x = (pa.x - ea * x.x) * ia; zt.y = (pa.y - ea * x.y) * ia;
  zt.z = (pa.z - ea * x.z) * ia; zt.w = (pa.w - ea * x.w) * ia;
  *(ushort4*)(zhat_bf + base + t * 4) = make_ushort4(f2bf(zh.x), f2bf(zh.y), f2bf(zh.z), f2bf(zh.w));
  *(ushort4*)(ztum_bf + base + t * 4) = make_ushort4(f2bf(zt.x), f2bf(zt.y), f2bf(zt.z), f2bf(zt.w));
  float nz2 = x.x*x.x + x.y*x.y + x.z*x.z + x.w*x.w;
  float nh2 = zh.x*zh.x + zh.y*zh.y + zh.z*zh.z + zh.w*zh.w;
  float dzh = x.x*zh.x + x.y*zh.y + x.z*zh.z + x.w*zh.w;
  float nb2 = zb.x*zb.x + zb.y*zb.y + zb.z*zb.z + zb.w*zb.w;
  float dzb = x.x*zb.x + x.y*zb.y + x.z*zb.z + x.w*zb.w;
  float s_nz2 = block_sum(nz2, sb);
  float s_nh2 = block_sum(nh2, sb);
  float s_dzh = block_sum(dzh, sb);
  float s_nb2 = block_sum(nb2, sb);
  float s_dzb = block_sum(dzb, sb);
  if (t == 0){
    float nz = sqrtf(s_nz2);
    nz_arr[i] = nz;
    float denA = fmaxf(nz, 1e-8f) * fmaxf(sqrtf(s_nh2), 1e-8f);
    float denB = fmaxf(nz, 1e-8f) * fmaxf(sqrtf(s_nb2), 1e-8f);
    atomicAdd(&accum[0], (1.f - s_dzh / denA) + (1.f - s_dzb / denB));
  }
}

// per-row: pt = C + D2 on the fly; dt = z.pt, ||pt||, dpn = z.(C+w), ||C+w||, g = z.w
__global__ __launch_bounds__(256) void k_rowred2(const float* __restrict__ z_all,
        const float* __restrict__ D2, const float* __restrict__ C,
        const float* __restrict__ w_norm, const float* __restrict__ nz_arr,
        float* __restrict__ dt_arr, float* __restrict__ g_arr, float* __restrict__ accum){
  __shared__ float sb[4];
  int i = blockIdx.x, t = threadIdx.x;
  size_t base = (size_t)i * D;
  float4 x  = ((const float4*)(z_all + base))[t];
  float4 d2 = ((const float4*)(D2 + base))[t];
  float4 c  = ((const float4*)(C + base))[t];
  float4 wv = ((const float4*)w_norm)[t];
  float4 pt = make_float4(c.x + d2.x, c.y + d2.y, c.z + d2.z, c.w + d2.w);
  float4 pn = make_float4(c.x + wv.x, c.y + wv.y, c.z + wv.z, c.w + wv.w);
  float dt   = x.x*pt.x + x.y*pt.y + x.z*pt.z + x.w*pt.w;
  float npt2 = pt.x*pt.x + pt.y*pt.y + pt.z*pt.z + pt.w*pt.w;
  float dpn  = x.x*pn.x + x.y*pn.y + x.z*pn.z + x.w*pn.w;
  float npn2 = pn.x*pn.x + pn.y*pn.y + pn.z*pn.z + pn.w*pn.w;
  float gg   = x.x*wv.x + x.y*wv.y + x.z*wv.z + x.w*wv.w;
  float s_dt   = block_sum(dt, sb);
  float s_npt2 = block_sum(npt2, sb);
  float s_dpn  = block_sum(dpn, sb);
  float s_npn2 = block_sum(npn2, sb);
  float s_g    = block_sum(gg, sb);
  if (t == 0){
    dt_arr[i] = s_dt; g_arr[i] = s_g;
    float nz = fmaxf(nz_arr[i], 1e-8f);
    float ct = s_dt  / (nz * fmaxf(sqrtf(s_npt2), 1e-8f));
    float cn = s_dpn / (nz * fmaxf(sqrtf(s_npn2), 1e-8f));
    atomicAdd(&accum[1], fmaxf(0.f, 1.f - (ct - cn)));
  }
}

__global__ __launch_bounds__(256) void k_combine(const float2* __restrict__ partials,
        const float* __restrict__ diagM, const float* __restrict__ dt,
        const float* __restrict__ g, float* __restrict__ accum){
  __shared__ float sb[4];
  int i = blockIdx.x * 256 + threadIdx.x;
  float m = -1e30f, S = 0.f;
  for (int c = 0; c < NCHUNK; ++c){
    float2 p = partials[(size_t)c * BTOT + i];
    float nm = fmaxf(m, p.x);
    S = S * __expf(m - nm) + p.y * __expf(p.x - nm);
    m = nm;
  }
  float vold = diagM[i];
  float vnew = dt[i] - g[i];
  float nm = fmaxf(m, vnew);
  float S2 = S * __expf(m - nm) - __expf(vold - nm) + __expf(vnew - nm);
  float lse = g[i] + nm + logf(S2);
  float contrib = lse - dt[i];
  float tot = block_sum(contrib, sb);
  if (threadIdx.x == 0) atomicAdd(&accum[2], tot);
}

__global__ void k_final(const float* __restrict__ accum, float* __restrict__ out){
  out[0] = accum[2] / (float)BTOT;
  out[1] = (accum[0] + accum[1]) / (float)BTOT;
}

// ---------------- launch ----------------
extern "C" void kernel_launch(void* const* d_in, const int* in_sizes, int n_in,
                              void* d_out, int out_size, void* d_ws, size_t ws_size,
                              hipStream_t stream){
  const float* z_low    = (const float*)d_in[0];
  const float* z_high   = (const float*)d_in[1];
  const float* z_bar    = (const float*)d_in[2];
  const float* z_normal = (const float*)d_in[3];
  const float* Wa1      = (const float*)d_in[4];
  const float* ba1      = (const float*)d_in[5];
  const float* Wa2      = (const float*)d_in[6];
  const float* ba2      = (const float*)d_in[7];   // dropped: softmax shift-invariant
  const float* W0       = (const float*)d_in[8];
  const float* b0       = (const float*)d_in[9];
  const float* W1       = (const float*)d_in[10];
  const float* b1       = (const float*)d_in[11];
  float* ws = (float*)d_ws;
  unsigned short* bw = (unsigned short*)(ws + BF_BASE_F);
  float* out = (float*)d_out;
  (void)ba2;

  k_prep<<<dim3(BTOT, 1, 3), dim3(256), 0, stream>>>(z_low, z_high, z_normal, z_bar,
      ws + OFF_ZALL, bw + BF_ZALLN, bw + BF_ZBAR);
  k_tconv3<<<dim3(32, 32, 3), dim3(256), 0, stream>>>(W0, W1, Wa1,
      bw + BF_W0T, bw + BF_W1T, bw + BF_WA1T);
  k_zero13<<<dim3(53), dim3(256), 0, stream>>>(ws);

  // scores over [z_all ; z_normal] in one call (M = 8192)
  k_scores_bf<<<dim3(2, 64), dim3(256), 0, stream>>>(bw + BF_ZALLN, bw + BF_WA1T,
      ba1, Wa2, ws + OFF_SALL);

  k_stats<<<dim3(1), dim3(256), 0, stream>>>(ws + OFF_SALL, ws + OFF_SNORM,
      ws + OFF_EGRP, ws + OFF_ENORM, ws + OFF_STATS);

  k_pvec<<<dim3(1, 256, 3), dim3(256), 0, stream>>>(ws + OFF_ZALL, z_normal,
      ws + OFF_EGRP, ws + OFF_ENORM, ws + OFF_PLOW);

  k_smallvec<<<dim3(4), dim3(256), 0, stream>>>(ws + OFF_PLOW, ws + OFF_STATS,
      b0, b1, ws + OFF_PALL, ws + OFF_ZNV, ws + OFF_BIASC);

  k_wnorm<<<dim3(4, 8), dim3(256), 0, stream>>>(ws + OFF_ZNV, W0, ws + OFF_WNORM);

  k_zhat<<<dim3(BTOT), dim3(256), 0, stream>>>(ws + OFF_ZALL, z_bar,
      ws + OFF_EGRP, ws + OFF_STATS,
      ws + OFF_PLOW, ws + OFF_PHIGH, ws + OFF_PALL,
      bw + BF_ZHAT, bw + BF_ZTUM, ws + OFF_NZ, ws + OFF_ACC);

  // z=0: C = zhat@W0 + zbar@W1 + biasC ; z=1: D2 = ztum@W0
  k_gemm_cpt<<<dim3(8, 32, 2), dim3(256), 0, stream>>>(bw + BF_ZHAT, bw + BF_ZBAR,
      bw + BF_ZTUM, bw + BF_W0T, bw + BF_W1T, ws + OFF_BIASC,
      ws + OFF_C, bw + BF_C, ws + OFF_D2);

  k_rowred2<<<dim3(BTOT), dim3(256), 0, stream>>>(ws + OFF_ZALL, ws + OFF_D2,
      ws + OFF_C, ws + OFF_WNORM, ws + OFF_NZ, ws + OFF_DT, ws + OFF_G, ws + OFF_ACC);

  k_gemm_lse<<<dim3(32, 16), dim3(256), 0, stream>>>(bw + BF_ZALLN, bw + BF_C,
      (float2*)(ws + OFF_PART), ws + OFF_DIAG);

  k_combine<<<dim3(16), dim3(256), 0, stream>>>((const float2*)(ws + OFF_PART),
      ws + OFF_DIAG, ws + OFF_DT, ws + OFF_G, ws + OFF_ACC);

  k_final<<<dim3(1), dim3(1), 0, stream>>>(ws + OFF_ACC, out);
}

// Round 8
// 388.122 us; speedup vs baseline: 1.0615x; 1.0615x over previous
//
#include <hip/hip_runtime.h>
#include <math.h>

#define D     1024
#define H     256
#define BLOW  2048
#define BTOT  4096
#define NCHUNK 64   // 4096 / 64 col chunks (per-wave) in the NT-LSE GEMM

using bf16x8 = __attribute__((ext_vector_type(8))) __bf16;
using f32x4  = __attribute__((ext_vector_type(4))) float;

// ---------------- workspace layout ----------------
// fp32 region (float units)
static const size_t OFF_ZALL = 0;                 // 4096*1024
static const size_t OFF_D2   = 4194304;           // D2 = z_tumor @ W0 (fp32)
static const size_t T0       = 8388608;
static const size_t OFF_SALL = T0;                // 4096  (s_norm follows contiguously)
static const size_t OFF_SNORM= T0 + 4096;         // 4096
static const size_t OFF_EGRP = T0 + 8192;         // 4096
static const size_t OFF_ENORM= T0 + 16384;        // 4096
static const size_t OFF_PLOW = T0 + 20480;        // 1024 x4 contiguous
static const size_t OFF_PALL = T0 + 23552;
static const size_t OFF_ZNV  = T0 + 24576;        // 1024
static const size_t OFF_WNORM= T0 + 25600;        // 1024
static const size_t OFF_BIASC= T0 + 26624;        // 1024
static const size_t OFF_STATS= T0 + 27648;        // 16
static const size_t OFF_ACC  = T0 + 27664;        // 16
static const size_t OFF_NZ   = T0 + 27680;        // 4096
static const size_t OFF_DT   = T0 + 31776;        // 4096
static const size_t OFF_G    = T0 + 35872;        // 4096
static const size_t OFF_DIAG = T0 + 39968;        // 4096
static const size_t OFF_PART = T0 + 44064;        // float2[64][4096] = 524288 floats
static const size_t BF_BASE_F = 8972288;          // bf16 region start (float units)
// bf16 offsets (ushort units)
static const size_t BF_ZALLN= 0;                  // [z_all(4096) ; z_normal(4096)] x 1024
static const size_t BF_ZCAT = 8388608;            // 4096 x 2048: [zhat | zbar]
static const size_t BF_ZTUM = 16777216;           // 4096 x 1024
static const size_t BF_C    = 20971520;           // 4096 x 1024
static const size_t BF_WCAT = 25165824;           // 1024 x 2048: [W0T | W1T]
static const size_t BF_WA1T = 27262976;           // 256 x 1024

// ---------------- helpers ----------------
__device__ inline unsigned short f2bf(float f){
  unsigned u = __float_as_uint(f);
  u += 0x7fffu + ((u >> 16) & 1u);
  return (unsigned short)(u >> 16);
}
__device__ inline float bf2f(unsigned short u){
  return __uint_as_float(((unsigned)u) << 16);
}
__device__ inline float wave_sum(float v){
#pragma unroll
  for (int o = 32; o > 0; o >>= 1) v += __shfl_xor(v, o);
  return v;
}
__device__ inline float wave_maxf(float v){
#pragma unroll
  for (int o = 32; o > 0; o >>= 1) v = fmaxf(v, __shfl_xor(v, o));
  return v;
}
__device__ inline float block_sum(float v, float* sb){
  v = wave_sum(v);
  __syncthreads();
  if ((threadIdx.x & 63) == 0) sb[threadIdx.x >> 6] = v;
  __syncthreads();
  return sb[0] + sb[1] + sb[2] + sb[3];
}
__device__ inline float block_maxf(float v, float* sb){
  v = wave_maxf(v);
  __syncthreads();
  if ((threadIdx.x & 63) == 0) sb[threadIdx.x >> 6] = v;
  __syncthreads();
  return fmaxf(fmaxf(sb[0], sb[1]), fmaxf(sb[2], sb[3]));
}

// async global->LDS, 16 B per lane (dest = wave-uniform base + lane*16)
__device__ inline void gload16(const unsigned short* g, unsigned short* l){
  __builtin_amdgcn_global_load_lds(
      (const __attribute__((address_space(1))) unsigned int*)g,
      (__attribute__((address_space(3))) unsigned int*)l, 16, 0, 0);
}

// ---------------- fused prep ----------------
__global__ __launch_bounds__(256) void k_prep(const float* __restrict__ zl,
        const float* __restrict__ zh, const float* __restrict__ znorm,
        const float* __restrict__ zbar, float* __restrict__ za,
        unsigned short* __restrict__ zalln_bf, unsigned short* __restrict__ zcat_bf){
  int row = blockIdx.x, t = threadIdx.x, job = blockIdx.z;
  if (job == 0){
    const float4* src = (const float4*)((row < BLOW) ? (zl + (size_t)row * D)
                                                     : (zh + (size_t)(row - BLOW) * D));
    float4 v = src[t];
    ((float4*)(za + (size_t)row * D))[t] = v;
    *(ushort4*)(zalln_bf + (size_t)row * D + t * 4) =
        make_ushort4(f2bf(v.x), f2bf(v.y), f2bf(v.z), f2bf(v.w));
  } else if (job == 1){
    float4 v = ((const float4*)(znorm + (size_t)row * D))[t];
    *(ushort4*)(zalln_bf + (size_t)(BTOT + row) * D + t * 4) =
        make_ushort4(f2bf(v.x), f2bf(v.y), f2bf(v.z), f2bf(v.w));
  } else {
    // z_bar -> ZCAT[row][1024 + 0..1023]
    float4 v = ((const float4*)(zbar + (size_t)row * D))[t];
    *(ushort4*)(zcat_bf + (size_t)row * 2048 + 1024 + t * 4) =
        make_ushort4(f2bf(v.x), f2bf(v.y), f2bf(v.z), f2bf(v.w));
  }
}

// transpose+convert weights: W0 -> WCAT[:,0:1024], W1 -> WCAT[:,1024:2048], Wa1 -> Wa1T
__global__ __launch_bounds__(256) void k_tconv3(const float* __restrict__ W0,
        const float* __restrict__ W1, const float* __restrict__ Wa1,
        unsigned short* __restrict__ WCAT, unsigned short* __restrict__ Wa1T){
  __shared__ float tile[32][33];
  int z = blockIdx.z;
  const float* in; unsigned short* out; int C, ostride;
  if (z == 0){ in = W0; out = WCAT; C = D; ostride = 2048; }
  else if (z == 1){ in = W1; out = WCAT + 1024; C = D; ostride = 2048; }
  else { if (blockIdx.x >= 8) return; in = Wa1; out = Wa1T; C = H; ostride = 1024; }
  int t = threadIdx.x;
  int lr = t >> 3;
  int lc = (t & 7) << 2;
  int gr = blockIdx.y * 32, gc = blockIdx.x * 32;
  float4 v = *(const float4*)(in + (size_t)(gr + lr) * C + gc + lc);
  tile[lr][lc + 0] = v.x; tile[lr][lc + 1] = v.y; tile[lr][lc + 2] = v.z; tile[lr][lc + 3] = v.w;
  __syncthreads();
  ushort4 o = make_ushort4(f2bf(tile[lc + 0][lr]), f2bf(tile[lc + 1][lr]),
                           f2bf(tile[lc + 2][lr]), f2bf(tile[lc + 3][lr]));
  *(ushort4*)(out + (size_t)(gc + lr) * ostride + gr + lc) = o;
}

// zero the scattered accumulator ranges in one launch
__global__ __launch_bounds__(256) void k_zero13(float* __restrict__ ws){
  int i = blockIdx.x * 256 + threadIdx.x;
  if (i < 8192) ws[OFF_SALL + i] = 0.f;                   // s_all + s_norm
  else if (i < 12288) ws[OFF_PLOW + i - 8192] = 0.f;      // P_low..P_all
  else if (i < 13312) ws[OFF_WNORM + i - 12288] = 0.f;
  else if (i < 13328) ws[OFF_ACC + i - 13312] = 0.f;
}

// ---------------- 128x128 counted-vmcnt double-buffered core ----------------
// 4 waves, 64x64 each, BK=32, linear LDS [128][32] bf16 per operand, 2 buffers.
// Raw s_barrier + counted s_waitcnt vmcnt(4): the 4 prefetch loads into `nxt`
// stay in flight across the barrier; only `buf`'s 4 (older) are waited on.
// sA/sB: row strides (elements); K: reduction length (multiple of 32).
__device__ inline void mfma_core_cv(const unsigned short* __restrict__ A, int sA,
                                    const unsigned short* __restrict__ B, int sB,
                                    int K, int row0, int col0,
                                    unsigned short* lds, f32x4 acc[4][4]){
  int t = threadIdx.x;
  int l = t & 63, w = t >> 6;
  int wrow = w >> 1, wcol = w & 1;
  int g = l >> 4, c15 = l & 15;
  const unsigned short* a0 = A + (size_t)(row0 + (t >> 2)) * sA + ((t & 3) << 3);
  const unsigned short* a1 = a0 + (size_t)64 * sA;
  const unsigned short* b0 = B + (size_t)(col0 + (t >> 2)) * sB + ((t & 3) << 3);
  const unsigned short* b1 = b0 + (size_t)64 * sB;
  int sd = w * 512;
  int abase = (wrow * 64 + c15) * 32 + g * 8;
  int bbase = 4096 + (wcol * 64 + c15) * 32 + g * 8;
  unsigned short* buf = lds;
  unsigned short* nxt = lds + 8192;
  // prologue: stage tile 0 into buf (4 loads in flight)
  gload16(a0, buf + sd);
  gload16(a1, buf + 2048 + sd);
  gload16(b0, buf + 4096 + sd);
  gload16(b1, buf + 6144 + sd);
  for (int kb = 0; kb < K; kb += 32){
    if (kb + 32 < K){
      gload16(a0 + kb + 32, nxt + sd);
      gload16(a1 + kb + 32, nxt + 2048 + sd);
      gload16(b0 + kb + 32, nxt + 4096 + sd);
      gload16(b1 + kb + 32, nxt + 6144 + sd);
      asm volatile("s_waitcnt vmcnt(4)" ::: "memory");   // buf's 4 landed; nxt's 4 in flight
    } else {
      asm volatile("s_waitcnt vmcnt(0)" ::: "memory");   // last tile: drain
    }
    __builtin_amdgcn_sched_barrier(0);
    __builtin_amdgcn_s_barrier();                        // all waves: buf populated
    __builtin_amdgcn_sched_barrier(0);
    bf16x8 af[4], bfr[4];
#pragma unroll
    for (int m = 0; m < 4; ++m) af[m]  = *(const bf16x8*)&buf[abase + m * 512];
#pragma unroll
    for (int n = 0; n < 4; ++n) bfr[n] = *(const bf16x8*)&buf[bbase + n * 512];
#pragma unroll
    for (int m = 0; m < 4; ++m)
#pragma unroll
      for (int n = 0; n < 4; ++n)
        acc[m][n] = __builtin_amdgcn_mfma_f32_16x16x32_bf16(af[m], bfr[n], acc[m][n], 0, 0, 0);
    __builtin_amdgcn_sched_barrier(0);
    __builtin_amdgcn_s_barrier();                        // all waves done reading buf
    __builtin_amdgcn_sched_barrier(0);
    unsigned short* tmp = buf; buf = nxt; nxt = tmp;
  }
}

// scores: S[row] += sum_col tanh(z@Wa1 + ba1)[col] * Wa2[col]  (ba2 dropped: softmax-invariant)
__global__ __launch_bounds__(256) void k_scores_bf(const unsigned short* __restrict__ Zbf,
        const unsigned short* __restrict__ Wa1T, const float* __restrict__ ba1,
        const float* __restrict__ Wa2, float* __restrict__ S){
  __shared__ __align__(16) unsigned short smem[16384];
  f32x4 acc[4][4];
  f32x4 zz = {0.f, 0.f, 0.f, 0.f};
#pragma unroll
  for (int m = 0; m < 4; ++m)
#pragma unroll
    for (int n = 0; n < 4; ++n) acc[m][n] = zz;
  int row0 = blockIdx.y * 128, col0 = blockIdx.x * 128;
  mfma_core_cv(Zbf, 1024, Wa1T, 1024, 1024, row0, col0, smem, acc);
  int t = threadIdx.x, l = t & 63, w = t >> 6, wrow = w >> 1, wcol = w & 1;
  int g = l >> 4, c15 = l & 15;
#pragma unroll
  for (int m = 0; m < 4; ++m){
#pragma unroll
    for (int r = 0; r < 4; ++r){
      float v = 0.f;
#pragma unroll
      for (int n = 0; n < 4; ++n){
        int col = col0 + wcol * 64 + n * 16 + c15;
        float x = acc[m][n][r] + ba1[col];
        float e = __expf(2.f * x);
        v += (1.f - 2.f / (e + 1.f)) * Wa2[col];
      }
      v += __shfl_xor(v, 1); v += __shfl_xor(v, 2); v += __shfl_xor(v, 4); v += __shfl_xor(v, 8);
      if (c15 == 0) atomicAdd(&S[row0 + wrow * 64 + m * 16 + 4 * g + r], v);
    }
  }
}

// C / D2 kernel, grid (8, 32, 2):
// z=0: Cbf = bf16( ZCAT . WCAT^T + biasC )   (K=2048: zhat@W0 + zbar@W1 fused)
// z=1: D2  = ztum @ W0  (fp32; B = WCAT rows' first 1024 = W0T)
__global__ __launch_bounds__(256) void k_gemm_cd(const unsigned short* __restrict__ ZCAT,
        const unsigned short* __restrict__ ZTUM, const unsigned short* __restrict__ WCAT,
        const float* __restrict__ biasC, unsigned short* __restrict__ Cbf,
        float* __restrict__ D2){
  __shared__ __align__(16) unsigned short smem[16384];
  f32x4 acc[4][4];
  f32x4 zz = {0.f, 0.f, 0.f, 0.f};
#pragma unroll
  for (int m = 0; m < 4; ++m)
#pragma unroll
    for (int n = 0; n < 4; ++n) acc[m][n] = zz;
  int row0 = blockIdx.y * 128, col0 = blockIdx.x * 128;
  int t = threadIdx.x, l = t & 63, w = t >> 6, wrow = w >> 1, wcol = w & 1;
  int g = l >> 4, c15 = l & 15;
  if (blockIdx.z == 0){
    mfma_core_cv(ZCAT, 2048, WCAT, 2048, 2048, row0, col0, smem, acc);
#pragma unroll
    for (int m = 0; m < 4; ++m){
      int row = row0 + wrow * 64 + m * 16 + 4 * g;
#pragma unroll
      for (int n = 0; n < 4; ++n){
        int col = col0 + wcol * 64 + n * 16 + c15;
        float bv = biasC[col];
#pragma unroll
        for (int r = 0; r < 4; ++r)
          Cbf[(size_t)(row + r) * 1024 + col] = f2bf(acc[m][n][r] + bv);
      }
    }
  } else {
    mfma_core_cv(ZTUM, 1024, WCAT, 2048, 1024, row0, col0, smem, acc);
#pragma unroll
    for (int m = 0; m < 4; ++m){
      int row = row0 + wrow * 64 + m * 16 + 4 * g;
#pragma unroll
      for (int n = 0; n < 4; ++n){
        int col = col0 + wcol * 64 + n * 16 + c15;
#pragma unroll
        for (int r = 0; r < 4; ++r)
          D2[(size_t)(row + r) * 1024 + col] = acc[m][n][r];
      }
    }
  }
}

// NT GEMM M = z_all . C^T with fused per-64col-chunk row (max,sumexp) partials + diag
__global__ __launch_bounds__(256) void k_gemm_lse(const unsigned short* __restrict__ A,
        const unsigned short* __restrict__ B, float2* __restrict__ partials,
        float* __restrict__ diagM){
  __shared__ __align__(16) unsigned short smem[16384];
  f32x4 acc[4][4];
  f32x4 zz = {0.f, 0.f, 0.f, 0.f};
#pragma unroll
  for (int m = 0; m < 4; ++m)
#pragma unroll
    for (int n = 0; n < 4; ++n) acc[m][n] = zz;
  int row0 = blockIdx.y * 128, col0 = blockIdx.x * 128;
  mfma_core_cv(A, 1024, B, 1024, 1024, row0, col0, smem, acc);
  int t = threadIdx.x, l = t & 63, w = t >> 6, wrow = w >> 1, wcol = w & 1;
  int g = l >> 4, c15 = l & 15;
  int chunk = blockIdx.x * 2 + wcol;
#pragma unroll
  for (int m = 0; m < 4; ++m){
#pragma unroll
    for (int r = 0; r < 4; ++r){
      float lm = acc[m][0][r];
#pragma unroll
      for (int n = 1; n < 4; ++n) lm = fmaxf(lm, acc[m][n][r]);
      lm = fmaxf(lm, __shfl_xor(lm, 1));
      lm = fmaxf(lm, __shfl_xor(lm, 2));
      lm = fmaxf(lm, __shfl_xor(lm, 4));
      lm = fmaxf(lm, __shfl_xor(lm, 8));
      float ls = 0.f;
#pragma unroll
      for (int n = 0; n < 4; ++n) ls += __expf(acc[m][n][r] - lm);
      ls += __shfl_xor(ls, 1); ls += __shfl_xor(ls, 2); ls += __shfl_xor(ls, 4); ls += __shfl_xor(ls, 8);
      if (c15 == 0)
        partials[(size_t)chunk * BTOT + (row0 + wrow * 64 + m * 16 + 4 * g + r)] = make_float2(lm, ls);
    }
  }
  if (blockIdx.x == blockIdx.y && wrow == wcol && ((c15 >> 2) == g)){
#pragma unroll
    for (int m = 0; m < 4; ++m)
      diagM[row0 + wrow * 64 + m * 16 + c15] = acc[m][m][c15 & 3];
  }
}

// ---------------- softmax stats (register-resident, one global pass) ----------------
__global__ __launch_bounds__(256) void k_stats(const float* __restrict__ s_all,
        const float* __restrict__ s_norm, float* __restrict__ e_grp,
        float* __restrict__ e_norm, float* __restrict__ stats){
  __shared__ float sb[4];
  int t = threadIdx.x;
  float va[16], vn[16];
#pragma unroll
  for (int j = 0; j < 16; ++j) va[j] = s_all[t + 256 * j];
#pragma unroll
  for (int j = 0; j < 16; ++j) vn[j] = s_norm[t + 256 * j];
  float m = -1e30f;
#pragma unroll
  for (int j = 0; j < 8; ++j) m = fmaxf(m, va[j]);
  float ml = block_maxf(m, sb);
  m = -1e30f;
#pragma unroll
  for (int j = 8; j < 16; ++j) m = fmaxf(m, va[j]);
  float mh = block_maxf(m, sb);
  m = -1e30f;
#pragma unroll
  for (int j = 0; j < 16; ++j) m = fmaxf(m, vn[j]);
  float mn = block_maxf(m, sb);
  float ma = fmaxf(ml, mh);
  float a = 0.f;
#pragma unroll
  for (int j = 0; j < 8; ++j){ float e = __expf(va[j] - ml); e_grp[t + 256 * j] = e; a += e; }
  float tl = block_sum(a, sb);
  a = 0.f;
#pragma unroll
  for (int j = 8; j < 16; ++j){ float e = __expf(va[j] - mh); e_grp[t + 256 * j] = e; a += e; }
  float th = block_sum(a, sb);
  a = 0.f;
#pragma unroll
  for (int j = 0; j < 16; ++j){ float e = __expf(vn[j] - mn); e_norm[t + 256 * j] = e; a += e; }
  float tn = block_sum(a, sb);
  if (t == 0){
    float sl = __expf(ml - ma), sh = __expf(mh - ma);
    stats[0] = ml; stats[1] = tl; stats[2] = mh; stats[3] = th;
    stats[4] = ma; stats[5] = tl * sl + th * sh; stats[6] = mn; stats[7] = tn;
    stats[8] = sl; stats[9] = sh;
  }
}

// P_g[col] = sum_rows e_row * x[row][col]; groups: 0 low, 1 high, 2 norm.
__global__ __launch_bounds__(256) void k_pvec(const float* __restrict__ z_all,
        const float* __restrict__ z_normal, const float* __restrict__ e_grp,
        const float* __restrict__ e_norm, float* __restrict__ P){
  int gz = blockIdx.z;
  const float* X; const float* E; float* Pg; int nr;
  if (gz == 0){ X = z_all;                         E = e_grp;        Pg = P;        nr = BLOW; }
  else if (gz == 1){ X = z_all + (size_t)BLOW * D; E = e_grp + BLOW; Pg = P + 1024; nr = BLOW; }
  else { X = z_normal;                             E = e_norm;       Pg = P + 2048; nr = BTOT; }
  int r0 = blockIdx.y * 16;
  if (r0 >= nr) return;
  int c4 = threadIdx.x * 4;
  float4 a = make_float4(0.f, 0.f, 0.f, 0.f);
#pragma unroll 4
  for (int r = r0; r < r0 + 16; ++r){
    float e = E[r];
    float4 x = *(const float4*)(X + (size_t)r * D + c4);
    a.x = fmaf(e, x.x, a.x); a.y = fmaf(e, x.y, a.y);
    a.z = fmaf(e, x.z, a.z); a.w = fmaf(e, x.w, a.w);
  }
  atomicAdd(&Pg[c4 + 0], a.x);
  atomicAdd(&Pg[c4 + 1], a.y);
  atomicAdd(&Pg[c4 + 2], a.z);
  atomicAdd(&Pg[c4 + 3], a.w);
}

// P_all = sl*P_low + sh*P_high; znv = P_norm / tn; biasC = 2 b0 + b1
__global__ __launch_bounds__(256) void k_smallvec(const float* __restrict__ P,
        const float* __restrict__ stats, const float* __restrict__ b0,
        const float* __restrict__ b1, float* __restrict__ P_all,
        float* __restrict__ znv, float* __restrict__ biasC){
  int c = blockIdx.x * 256 + threadIdx.x;
  znv[c] = P[2048 + c] / stats[7];
  biasC[c] = 2.f * b0[c] + b1[c];
  P_all[c] = stats[8] * P[c] + stats[9] * P[1024 + c];
}

__global__ __launch_bounds__(256) void k_wnorm(const float* __restrict__ znv,
        const float* __restrict__ W0, float* __restrict__ w_norm){
  int col = blockIdx.x * 256 + threadIdx.x;
  int kc = blockIdx.y;
  float a = 0.f;
  for (int k = kc * 128; k < kc * 128 + 128; ++k)
    a = fmaf(znv[k], W0[(size_t)k * D + col], a);
  atomicAdd(&w_norm[col], a);
}

// z_hat / z_tumor rows (bf16: zhat -> ZCAT[:,0:1024], ztum -> ZTUM) + cos reductions
__global__ __launch_bounds__(256) void k_zhat(const float* __restrict__ z_all,
        const float* __restrict__ z_bar, const float* __restrict__ e_grp,
        const float* __restrict__ stats,
        const float* __restrict__ P_low, const float* __restrict__ P_high,
        const float* __restrict__ P_all, unsigned short* __restrict__ zcat_bf,
        unsigned short* __restrict__ ztum_bf, float* __restrict__ nz_arr,
        float* __restrict__ accum){
  __shared__ float sb[4];
  int i = blockIdx.x, t = threadIdx.x;
  const float* Pg = (i < BLOW) ? P_low : P_high;
  float Tg = (i < BLOW) ? stats[1] : stats[3];
  float Ta = stats[5];
  float eg = e_grp[i];
  float ea = eg * ((i < BLOW) ? stats[8] : stats[9]);
  float ig = 1.f / (Tg - eg), ia = 1.f / (Ta - ea);
  size_t base = (size_t)i * D;
  float4 x  = ((const float4*)(z_all + base))[t];
  float4 pg = ((const float4*)Pg)[t];
  float4 pa = ((const float4*)P_all)[t];
  float4 zb = ((const float4*)(z_bar + base))[t];
  float4 zh, zt;
  zh.x = (pg.x - eg * x.x) * ig; zh.y = (pg.y - eg * x.y) * ig;
  zh.z = (pg.z - eg * x.z) * ig; zh.w = (pg.w - eg * x.w) * ig;
  zt.x = (pa.x - ea * x.x) * ia; zt.y = (pa.y - ea * x.y) * ia;
  zt.z = (pa.z - ea * x.z) * ia; zt.w = (pa.w - ea * x.w) * ia;
  *(ushort4*)(zcat_bf + (size_t)i * 2048 + t * 4) =
      make_ushort4(f2bf(zh.x), f2bf(zh.y), f2bf(zh.z), f2bf(zh.w));
  *(ushort4*)(ztum_bf + base + t * 4) = make_ushort4(f2bf(zt.x), f2bf(zt.y), f2bf(zt.z), f2bf(zt.w));
  float nz2 = x.x*x.x + x.y*x.y + x.z*x.z + x.w*x.w;
  float nh2 = zh.x*zh.x + zh.y*zh.y + zh.z*zh.z + zh.w*zh.w;
  float dzh = x.x*zh.x + x.y*zh.y + x.z*zh.z + x.w*zh.w;
  float nb2 = zb.x*zb.x + zb.y*zb.y + zb.z*zb.z + zb.w*zb.w;
  float dzb = x.x*zb.x + x.y*zb.y + x.z*zb.z + x.w*zb.w;
  float s_nz2 = block_sum(nz2, sb);
  float s_nh2 = block_sum(nh2, sb);
  float s_dzh = block_sum(dzh, sb);
  float s_nb2 = block_sum(nb2, sb);
  float s_dzb = block_sum(dzb, sb);
  if (t == 0){
    float nz = sqrtf(s_nz2);
    nz_arr[i] = nz;
    float denA = fmaxf(nz, 1e-8f) * fmaxf(sqrtf(s_nh2), 1e-8f);
    float denB = fmaxf(nz, 1e-8f) * fmaxf(sqrtf(s_nb2), 1e-8f);
    atomicAdd(&accum[0], (1.f - s_dzh / denA) + (1.f - s_dzb / denB));
  }
}

// per-row: C from Cbf (bf16); pt = C + D2; dt = z.pt, ||pt||, dpn = z.(C+w), ||C+w||, g = z.w
__global__ __launch_bounds__(256) void k_rowred2(const float* __restrict__ z_all,
        const float* __restrict__ D2, const unsigned short* __restrict__ Cbf,
        const float* __restrict__ w_norm, const float* __restrict__ nz_arr,
        float* __restrict__ dt_arr, float* __restrict__ g_arr, float* __restrict__ accum){
  __shared__ float sb[4];
  int i = blockIdx.x, t = threadIdx.x;
  size_t base = (size_t)i * D;
  float4 x  = ((const float4*)(z_all + base))[t];
  float4 d2 = ((const float4*)(D2 + base))[t];
  ushort4 cu = *(const ushort4*)(Cbf + base + t * 4);
  float4 c = make_float4(bf2f(cu.x), bf2f(cu.y), bf2f(cu.z), bf2f(cu.w));
  float4 wv = ((const float4*)w_norm)[t];
  float4 pt = make_float4(c.x + d2.x, c.y + d2.y, c.z + d2.z, c.w + d2.w);
  float4 pn = make_float4(c.x + wv.x, c.y + wv.y, c.z + wv.z, c.w + wv.w);
  float dt   = x.x*pt.x + x.y*pt.y + x.z*pt.z + x.w*pt.w;
  float npt2 = pt.x*pt.x + pt.y*pt.y + pt.z*pt.z + pt.w*pt.w;
  float dpn  = x.x*pn.x + x.y*pn.y + x.z*pn.z + x.w*pn.w;
  float npn2 = pn.x*pn.x + pn.y*pn.y + pn.z*pn.z + pn.w*pn.w;
  float gg   = x.x*wv.x + x.y*wv.y + x.z*wv.z + x.w*wv.w;
  float s_dt   = block_sum(dt, sb);
  float s_npt2 = block_sum(npt2, sb);
  float s_dpn  = block_sum(dpn, sb);
  float s_npn2 = block_sum(npn2, sb);
  float s_g    = block_sum(gg, sb);
  if (t == 0){
    dt_arr[i] = s_dt; g_arr[i] = s_g;
    float nz = fmaxf(nz_arr[i], 1e-8f);
    float ct = s_dt  / (nz * fmaxf(sqrtf(s_npt2), 1e-8f));
    float cn = s_dpn / (nz * fmaxf(sqrtf(s_npn2), 1e-8f));
    atomicAdd(&accum[1], fmaxf(0.f, 1.f - (ct - cn)));
  }
}

__global__ __launch_bounds__(256) void k_combine(const float2* __restrict__ partials,
        const float* __restrict__ diagM, const float* __restrict__ dt,
        const float* __restrict__ g, float* __restrict__ accum){
  __shared__ float sb[4];
  int i = blockIdx.x * 256 + threadIdx.x;
  float m = -1e30f, S = 0.f;
  for (int c = 0; c < NCHUNK; ++c){
    float2 p = partials[(size_t)c * BTOT + i];
    float nm = fmaxf(m, p.x);
    S = S * __expf(m - nm) + p.y * __expf(p.x - nm);
    m = nm;
  }
  float vold = diagM[i];
  float vnew = dt[i] - g[i];
  float nm = fmaxf(m, vnew);
  float S2 = S * __expf(m - nm) - __expf(vold - nm) + __expf(vnew - nm);
  float lse = g[i] + nm + logf(S2);
  float contrib = lse - dt[i];
  float tot = block_sum(contrib, sb);
  if (threadIdx.x == 0) atomicAdd(&accum[2], tot);
}

__global__ void k_final(const float* __restrict__ accum, float* __restrict__ out){
  out[0] = accum[2] / (float)BTOT;
  out[1] = (accum[0] + accum[1]) / (float)BTOT;
}

// ---------------- launch ----------------
extern "C" void kernel_launch(void* const* d_in, const int* in_sizes, int n_in,
                              void* d_out, int out_size, void* d_ws, size_t ws_size,
                              hipStream_t stream){
  const float* z_low    = (const float*)d_in[0];
  const float* z_high   = (const float*)d_in[1];
  const float* z_bar    = (const float*)d_in[2];
  const float* z_normal = (const float*)d_in[3];
  const float* Wa1      = (const float*)d_in[4];
  const float* ba1      = (const float*)d_in[5];
  const float* Wa2      = (const float*)d_in[6];
  const float* ba2      = (const float*)d_in[7];   // dropped: softmax shift-invariant
  const float* W0       = (const float*)d_in[8];
  const float* b0       = (const float*)d_in[9];
  const float* W1       = (const float*)d_in[10];
  const float* b1       = (const float*)d_in[11];
  float* ws = (float*)d_ws;
  unsigned short* bw = (unsigned short*)(ws + BF_BASE_F);
  float* out = (float*)d_out;
  (void)ba2;

  k_prep<<<dim3(BTOT, 1, 3), dim3(256), 0, stream>>>(z_low, z_high, z_normal, z_bar,
      ws + OFF_ZALL, bw + BF_ZALLN, bw + BF_ZCAT);
  k_tconv3<<<dim3(32, 32, 3), dim3(256), 0, stream>>>(W0, W1, Wa1,
      bw + BF_WCAT, bw + BF_WA1T);
  k_zero13<<<dim3(53), dim3(256), 0, stream>>>(ws);

  // scores over [z_all ; z_normal] in one call (M = 8192)
  k_scores_bf<<<dim3(2, 64), dim3(256), 0, stream>>>(bw + BF_ZALLN, bw + BF_WA1T,
      ba1, Wa2, ws + OFF_SALL);

  k_stats<<<dim3(1), dim3(256), 0, stream>>>(ws + OFF_SALL, ws + OFF_SNORM,
      ws + OFF_EGRP, ws + OFF_ENORM, ws + OFF_STATS);

  k_pvec<<<dim3(1, 256, 3), dim3(256), 0, stream>>>(ws + OFF_ZALL, z_normal,
      ws + OFF_EGRP, ws + OFF_ENORM, ws + OFF_PLOW);

  k_smallvec<<<dim3(4), dim3(256), 0, stream>>>(ws + OFF_PLOW, ws + OFF_STATS,
      b0, b1, ws + OFF_PALL, ws + OFF_ZNV, ws + OFF_BIASC);

  k_wnorm<<<dim3(4, 8), dim3(256), 0, stream>>>(ws + OFF_ZNV, W0, ws + OFF_WNORM);

  k_zhat<<<dim3(BTOT), dim3(256), 0, stream>>>(ws + OFF_ZALL, z_bar,
      ws + OFF_EGRP, ws + OFF_STATS,
      ws + OFF_PLOW, ws + OFF_PLOW + 1024, ws + OFF_PALL,
      bw + BF_ZCAT, bw + BF_ZTUM, ws + OFF_NZ, ws + OFF_ACC);

  // z=0: Cbf = ZCAT.WCAT^T + biasC (K=2048) ; z=1: D2 = ztum@W0
  k_gemm_cd<<<dim3(8, 32, 2), dim3(256), 0, stream>>>(bw + BF_ZCAT, bw + BF_ZTUM,
      bw + BF_WCAT, ws + OFF_BIASC, bw + BF_C, ws + OFF_D2);

  k_rowred2<<<dim3(BTOT), dim3(256), 0, stream>>>(ws + OFF_ZALL, ws + OFF_D2,
      bw + BF_C, ws + OFF_WNORM, ws + OFF_NZ, ws + OFF_DT, ws + OFF_G, ws + OFF_ACC);

  k_gemm_lse<<<dim3(32, 32), dim3(256), 0, stream>>>(bw + BF_ZALLN, bw + BF_C,
      (float2*)(ws + OFF_PART), ws + OFF_DIAG);

  k_combine<<<dim3(16), dim3(256), 0, stream>>>((const float2*)(ws + OFF_PART),
      ws + OFF_DIAG, ws + OFF_DT, ws + OFF_G, ws + OFF_ACC);

  k_final<<<dim3(1), dim3(1), 0, stream>>>(ws + OFF_ACC, out);
}